// Round 19
// baseline (121.909 us; speedup 1.0000x reference)
//
#include <hip/hip_runtime.h>
#include <hip/hip_fp16.h>

#define SS 2048
#define HH 30
#define KVHH 6
#define DD 64
#define HIDD 1920
#define NQKV 2688   // 1920 (q) + 384 (k) + 384 (v)

typedef __attribute__((ext_vector_type(4))) float  f32x4;
typedef __attribute__((ext_vector_type(4))) float  float4v;
typedef __attribute__((ext_vector_type(8))) _Float16 f16x8;
typedef __attribute__((ext_vector_type(4))) _Float16 f16x4;

// ---------------------------------------------------------------- RoPE cos/sin table: tab[s*32+j] = {cos(s*f_j), sin(s*f_j)}
__global__ __launch_bounds__(256) void rope_tab_init(float2* __restrict__ tab) {
    int idx = blockIdx.x * 256 + threadIdx.x;          // 0..65535 = s*32+j
    int s = idx >> 5, j = idx & 31;
    float f = exp2f(-13.287712379549449f * (float)j * (1.0f / 32.0f));
    float ang = (float)s * f;
    float sn, cs;
    sincosf(ang, &sn, &cs);
    tab[idx] = make_float2(cs, sn);
}

// ---------------------------------------------------------------- fused f32->f16 cvt (*alpha), 5 regions, 1024 elems/block
__global__ __launch_bounds__(256) void cvt_all(const float* __restrict__ hs,
                                               const float* __restrict__ Wq,
                                               const float* __restrict__ Wk,
                                               const float* __restrict__ Wv,
                                               const float* __restrict__ Wo,
                                               _Float16* __restrict__ hsb,
                                               _Float16* __restrict__ wqkvb,
                                               _Float16* __restrict__ wob,
                                               const float* __restrict__ qa,
                                               const float* __restrict__ ka,
                                               const float* __restrict__ va,
                                               const float* __restrict__ oa) {
    int b = blockIdx.x;
    const float* in; _Float16* out; float a; int base;
    if (b < 3840)      { in = hs; out = hsb;              a = 1.0f;  base = b; }
    else if (b < 7440) { in = Wq; out = wqkvb;            a = qa[0]; base = b - 3840; }
    else if (b < 8160) { in = Wk; out = wqkvb + 3686400;  a = ka[0]; base = b - 7440; }
    else if (b < 8880) { in = Wv; out = wqkvb + 4423680;  a = va[0]; base = b - 8160; }
    else               { in = Wo; out = wob;              a = oa[0]; base = b - 8880; }
    int i = base * 1024 + threadIdx.x * 4;
    float4v v = *(const float4v*)(in + i);
    f16x4 o;
    o[0] = (_Float16)(v[0] * a);
    o[1] = (_Float16)(v[1] * a);
    o[2] = (_Float16)(v[2] * a);
    o[3] = (_Float16)(v[3] * a);
    *(f16x4*)(out + i) = o;
}

// ---------------------------------------------------------------- shared GEMM pieces
// 64x128 tile, BK=64, 8 waves as 4M x 2N, wave sub-tile 16x64.
// 2-slot double buffer (48 KB), counted vmcnt(3) + raw barriers (R18 scheme).
#define GEMM_STAGE(buf, ktv)                                                                           \
    do {                                                                                               \
        {                                                                                              \
            int row = tid >> 3;                                                                        \
            int sl  = (tid & 7) ^ (row & 7);                                                           \
            const _Float16* gA = A + (size_t)(m0 + row) * K + (ktv) + sl * 8;                          \
            _Float16* lA = As[buf] + (size_t)(w * 64) * 8;                                             \
            __builtin_amdgcn_global_load_lds((const __attribute__((address_space(1))) unsigned int*)gA,\
                                             (__attribute__((address_space(3))) unsigned int*)lA, 16, 0, 0); \
        }                                                                                              \
        _Pragma("unroll")                                                                              \
        for (int it = 0; it < 2; ++it) {                                                               \
            int gg  = it * 512 + tid;                                                                  \
            int row = gg >> 3;                                                                         \
            int sl  = (gg & 7) ^ (row & 7);                                                            \
            const _Float16* gB = B + (size_t)(n0 + row) * K + (ktv) + sl * 8;                          \
            _Float16* lB = Bs[buf] + (size_t)(it * 512 + w * 64) * 8;                                  \
            __builtin_amdgcn_global_load_lds((const __attribute__((address_space(1))) unsigned int*)gB,\
                                             (__attribute__((address_space(3))) unsigned int*)lB, 16, 0, 0); \
        }                                                                                              \
    } while (0)

#define GEMM_BODY()                                                                                    \
    f32x4 acc[4];                                                                                      \
    _Pragma("unroll")                                                                                  \
    for (int b = 0; b < 4; ++b) acc[b] = (f32x4)0.0f;                                                  \
    GEMM_STAGE(0, 0);                                                                                  \
    const int nk = K >> 6;                                                                             \
    for (int t = 0; t < nk; ++t) {                                                                     \
        const int cur = t & 1;                                                                         \
        if (t + 1 < nk) {                                                                              \
            GEMM_STAGE(cur ^ 1, (t + 1) * 64);                                                         \
            asm volatile("s_waitcnt vmcnt(3)" ::: "memory");                                           \
        } else {                                                                                       \
            asm volatile("s_waitcnt vmcnt(0)" ::: "memory");                                           \
        }                                                                                              \
        __builtin_amdgcn_s_barrier();                                                                  \
        __builtin_amdgcn_sched_barrier(0);                                                             \
        _Pragma("unroll")                                                                              \
        for (int kk = 0; kk < 2; ++kk) {                                                               \
            f16x8 af, bf[4];                                                                           \
            {                                                                                          \
                int row = wm + (l & 15);                                                               \
                int s   = (kk * 4 + (l >> 4)) ^ (row & 7);                                             \
                af = *(const f16x8*)(As[cur] + row * 64 + s * 8);                                      \
            }                                                                                          \
            _Pragma("unroll")                                                                          \
            for (int fn = 0; fn < 4; ++fn) {                                                           \
                int row = wn + fn * 16 + (l & 15);                                                     \
                int s   = (kk * 4 + (l >> 4)) ^ (row & 7);                                             \
                bf[fn] = *(const f16x8*)(Bs[cur] + row * 64 + s * 8);                                  \
            }                                                                                          \
            _Pragma("unroll")                                                                          \
            for (int fn = 0; fn < 4; ++fn)                                                             \
                acc[fn] = __builtin_amdgcn_mfma_f32_16x16x32_f16(af, bf[fn], acc[fn], 0, 0, 0);        \
        }                                                                                              \
        __builtin_amdgcn_sched_barrier(0);                                                             \
        __builtin_amdgcn_s_barrier();                                                                  \
    }

// ---------------------------------------------------------------- QKV GEMM with fused LN+RoPE epilogue
__global__ __launch_bounds__(512) void gemm_qkv(const _Float16* __restrict__ A,
                                                const _Float16* __restrict__ B,
                                                const float* __restrict__ qlnw,
                                                const float* __restrict__ klnw,
                                                const float2* __restrict__ tab,
                                                _Float16* __restrict__ Qh,
                                                _Float16* __restrict__ Kh,
                                                _Float16* __restrict__ Vh,
                                                int M, int N, int K) {
    __shared__ __align__(16) _Float16 As[2][64 * 64];
    __shared__ __align__(16) _Float16 Bs[2][128 * 64];
    const int tid = threadIdx.x;
    const int l   = tid & 63;
    const int w   = tid >> 6;                 // 0..7
    const int wm  = (w >> 1) * 16;            // 4 waves in M (16 rows each)
    const int wn  = (w & 1) * 64;             // 2 waves in N
    const int g = l >> 4, li = l & 15;

    const int gx  = gridDim.x;
    const int nwg = gx * gridDim.y;
    int bid = blockIdx.y * gx + blockIdx.x;
    int lid = (bid & 7) * (nwg >> 3) + (bid >> 3);
    int gsz = gx * 8;
    int grp = lid / gsz;
    int r   = lid - grp * gsz;
    int bx  = r >> 3;
    int by  = grp * 8 + (r & 7);

    const int m0 = by * 64;
    const int n0 = bx * 128;

    GEMM_BODY();

    // ---- fused epilogue ----------------------------------------------------
    const int unit = (n0 >> 6) + (w & 1);
    if (unit < 36) {          // Q or K head: LayerNorm + RoPE
        const float* lwp = (unit < 30) ? (qlnw + unit * 64) : (klnw + (unit - 30) * 64);
        float lw[4];
#pragma unroll
        for (int fn = 0; fn < 4; ++fn) lw[fn] = lwp[fn * 16 + li];
        _Float16* outp = (unit < 30) ? (Qh + (size_t)unit * SS * 64)
                                     : (Kh + (size_t)(unit - 30) * SS * 64);
        const float qs = (unit < 30) ? 0.18033688011112042f : 1.0f;
#pragma unroll
        for (int j = 0; j < 4; ++j) {
            float x0 = acc[0][j], x1 = acc[1][j], x2 = acc[2][j], x3 = acc[3][j];
            float s1 = x0 + x1 + x2 + x3;
            float s2 = x0 * x0 + x1 * x1 + x2 * x2 + x3 * x3;
#pragma unroll
            for (int off = 1; off < 16; off <<= 1) {
                s1 += __shfl_xor(s1, off);
                s2 += __shfl_xor(s2, off);
            }
            float mu  = s1 * (1.0f / 64.0f);
            float var = s2 * (1.0f / 64.0f) - mu * mu;   // biased var
            float rst = rsqrtf(var + 1e-5f);
            float n0_ = (x0 - mu) * rst * lw[0];
            float n1_ = (x1 - mu) * rst * lw[1];
            float n2_ = (x2 - mu) * rst * lw[2];
            float n3_ = (x3 - mu) * rst * lw[3];
            int srow = m0 + wm + g * 4 + j;
            float2 cs0 = tab[srow * 32 + li];
            float2 cs1 = tab[srow * 32 + 16 + li];
            float o0 = (n0_ * cs0.x - n2_ * cs0.y) * qs;
            float o1 = (n1_ * cs1.x - n3_ * cs1.y) * qs;
            float o2 = (n2_ * cs0.x + n0_ * cs0.y) * qs;
            float o3 = (n3_ * cs1.x + n1_ * cs1.y) * qs;
            _Float16* rp = outp + (size_t)srow * 64 + li;
            rp[0]  = (_Float16)o0;
            rp[16] = (_Float16)o1;
            rp[32] = (_Float16)o2;
            rp[48] = (_Float16)o3;
        }
    } else {                  // V head: passthrough f16 store (head-major)
        _Float16* outp = Vh + (size_t)(unit - 36) * SS * 64;
#pragma unroll
        for (int j = 0; j < 4; ++j) {
            int srow = m0 + wm + g * 4 + j;
            _Float16* rp = outp + (size_t)srow * 64 + li;
            rp[0]  = (_Float16)acc[0][j];
            rp[16] = (_Float16)acc[1][j];
            rp[32] = (_Float16)acc[2][j];
            rp[48] = (_Float16)acc[3][j];
        }
    }
}

// ---------------------------------------------------------------- O-projection GEMM (f32 out)
__global__ __launch_bounds__(512) void gemm_bt_f16(const _Float16* __restrict__ A,
                                                   const _Float16* __restrict__ B,
                                                   float* __restrict__ C,
                                                   int M, int N, int K) {
    __shared__ __align__(16) _Float16 As[2][64 * 64];
    __shared__ __align__(16) _Float16 Bs[2][128 * 64];
    const int tid = threadIdx.x;
    const int l   = tid & 63;
    const int w   = tid >> 6;
    const int wm  = (w >> 1) * 16;
    const int wn  = (w & 1) * 64;

    const int gx  = gridDim.x;
    const int nwg = gx * gridDim.y;
    int bid = blockIdx.y * gx + blockIdx.x;
    int lid = (bid & 7) * (nwg >> 3) + (bid >> 3);
    int gsz = gx * 8;
    int grp = lid / gsz;
    int r   = lid - grp * gsz;
    int bx  = r >> 3;
    int by  = grp * 8 + (r & 7);

    const int m0 = by * 64;
    const int n0 = bx * 128;

    GEMM_BODY();

#pragma unroll
    for (int fn = 0; fn < 4; ++fn)
#pragma unroll
        for (int j = 0; j < 4; ++j) {
            int rr = m0 + wm + (l >> 4) * 4 + j;
            int cc = n0 + wn + fn * 16 + (l & 15);
            C[(size_t)rr * N + cc] = acc[fn][j];
        }
}

// ---------------------------------------------------------------- V transpose: Vh[h][s][d] -> Vt[h][d][s]
__global__ __launch_bounds__(256) void transpose_v(const _Float16* __restrict__ Vh,
                                                   _Float16* __restrict__ Vt) {
    __shared__ _Float16 T[64][68];
    const int s0 = blockIdx.x * 64;
    const int h  = blockIdx.y;
    const int tid = threadIdx.x;
#pragma unroll
    for (int pass = 0; pass < 2; ++pass) {
        int idx = pass * 256 + tid;
        int r = idx >> 3, d0 = (idx & 7) * 8;
        f16x8 v = *(const f16x8*)(Vh + ((size_t)(h * SS + s0 + r)) * 64 + d0);
#pragma unroll
        for (int j = 0; j < 8; ++j) T[r][d0 + j] = v[j];
    }
    __syncthreads();
#pragma unroll
    for (int pass = 0; pass < 2; ++pass) {
        int idx = pass * 256 + tid;
        int d = idx >> 3, c0 = (idx & 7) * 8;
        f16x8 o;
#pragma unroll
        for (int j = 0; j < 8; ++j) o[j] = T[c0 + j][d];
        *(f16x8*)(Vt + ((size_t)(h * 64 + d)) * SS + s0 + c0) = o;
    }
}

// ---------------------------------------------------------------- MFMA sliding-window attention
// R18 structure, with the P LDS bounce replaced by IN-REGISTER shuffles:
// softmax leaves pk[f][rp] (packed f16x2 of P[q=li][k=f*16+g*4+2rp..+1]) in
// VGPRs; the PV A-fragment word jp of half kk is pk[2kk+(g>>1)][jp&1] read
// from lane ((2g+(jp>>1))&3)*16+li (derived from k0=32kk+8g+2jp). Removes
// 8 ds_write + 4 ds_read + lgkm stall per chunk AND the 8 KB Ps buffer
// (LDS 40->32 KB, 5 blocks/CU cap).
#define ATTN_STAGE(buf, c)                                                                             \
    do {                                                                                               \
        _Pragma("unroll")                                                                              \
        for (int t = 0; t < 2; ++t) {                                                                  \
            int rloc = w * 16 + t * 8 + (l >> 3);                                                      \
            int ss = (l & 7) ^ (l >> 3);                                                               \
            const _Float16* gK = Kh + ((size_t)kvh * SS + (c) * 64 + rloc) * 64 + ss * 8;              \
            const _Float16* gV = Vt + ((size_t)kvh * 64 + rloc) * SS + (c) * 64 + ss * 8;              \
            _Float16* lK = Ks[buf] + (w * 16 + t * 8) * 64;                                            \
            _Float16* lV = Vs[buf] + (w * 16 + t * 8) * 64;                                            \
            __builtin_amdgcn_global_load_lds((const __attribute__((address_space(1))) unsigned int*)gK,\
                                             (__attribute__((address_space(3))) unsigned int*)lK, 16, 0, 0); \
            __builtin_amdgcn_global_load_lds((const __attribute__((address_space(1))) unsigned int*)gV,\
                                             (__attribute__((address_space(3))) unsigned int*)lV, 16, 0, 0); \
        }                                                                                              \
    } while (0)

__global__ __launch_bounds__(256) void attn_mfma(const _Float16* __restrict__ Qh,
                                                 const _Float16* __restrict__ Kh,
                                                 const _Float16* __restrict__ Vt,
                                                 _Float16* __restrict__ Ob) {
    __shared__ __align__(16) _Float16 Ks[2][64 * 64];
    __shared__ __align__(16) _Float16 Vs[2][64 * 64];

    const int qb = 31 - blockIdx.y;          // long blocks dispatch first
    const int h = blockIdx.x;                // x = head: balances qb across CUs
    const int Q0 = qb * 64;
    const int kvh = h / 5;
    const int tid = threadIdx.x, l = tid & 63, w = tid >> 6;
    const int g = l >> 4, li = l & 15;
    const int qabs = Q0 + w * 16 + li;
    const int qw = Q0 + w * 16;

    f16x8 qf[2];
#pragma unroll
    for (int dk = 0; dk < 2; ++dk)
        qf[dk] = *(const f16x8*)(Qh + ((size_t)h * SS + qabs) * 64 + dk * 32 + g * 8);
    asm volatile("s_waitcnt vmcnt(0)" ::: "memory");   // qf resolved before counting starts

    float m_i = -1e20f, l_i = 0.0f;          // floor -1e20: masked rows stay p=0
    f32x4 o[4];
#pragma unroll
    for (int fn = 0; fn < 4; ++fn) o[fn] = (f32x4)0.0f;

    const int c_lo = (Q0 >= 1023) ? ((Q0 - 1023) >> 6) : 0;
    const int c_hi = qb;

    ATTN_STAGE(0, c_lo);

    for (int c = c_lo; c <= c_hi; ++c) {
        const int nb = (c - c_lo) & 1;
        if (c < c_hi) {
            ATTN_STAGE(nb ^ 1, c + 1);                       // flies across both barriers
            asm volatile("s_waitcnt vmcnt(4)" ::: "memory"); // stage(c) landed
        } else {
            asm volatile("s_waitcnt vmcnt(0)" ::: "memory"); // last chunk: drain
        }
        __builtin_amdgcn_s_barrier();
        __builtin_amdgcn_sched_barrier(0);

        if (c * 64 <= qw + 15 && c * 64 + 63 >= qw - 1023) {
            const _Float16* Kb = Ks[nb];
            const _Float16* Vb = Vs[nb];
            const bool full = (c * 64 + 63 <= qw) && (c * 64 >= qw + 15 - 1023);

            f32x4 st[4];
#pragma unroll
            for (int f = 0; f < 4; ++f) st[f] = (f32x4)0.0f;
            __builtin_amdgcn_s_setprio(1);
#pragma unroll
            for (int dk = 0; dk < 2; ++dk) {
#pragma unroll
                for (int f = 0; f < 4; ++f) {
                    int ps = (dk * 4 + g) ^ (li & 7);
                    f16x8 kf = *(const f16x8*)(Kb + (f * 16 + li) * 64 + ps * 8);
                    st[f] = __builtin_amdgcn_mfma_f32_16x16x32_f16(kf, qf[dk], st[f], 0, 0, 0);
                }
            }
            __builtin_amdgcn_s_setprio(0);

            if (!full) {
#pragma unroll
                for (int f = 0; f < 4; ++f)
#pragma unroll
                    for (int reg = 0; reg < 4; ++reg) {
                        int kab = c * 64 + f * 16 + g * 4 + reg;
                        bool valid = (kab <= qabs) && (qabs - kab < 1024);
                        st[f][reg] = valid ? st[f][reg] : -1e30f;
                    }
            }
            float mx = -1e30f;
#pragma unroll
            for (int f = 0; f < 4; ++f)
#pragma unroll
                for (int reg = 0; reg < 4; ++reg) mx = fmaxf(mx, st[f][reg]);
            mx = fmaxf(mx, __shfl_xor(mx, 16));
            mx = fmaxf(mx, __shfl_xor(mx, 32));

            if (__any(mx > m_i + 8.0f)) {        // defer-max: P bounded by 2^8
                float m_new = fmaxf(m_i, mx);
                float corr = exp2f(m_i - m_new);
                m_i = m_new;
                l_i *= corr;
                float c0 = __shfl(corr, g * 4 + 0);
                float c1 = __shfl(corr, g * 4 + 1);
                float c2 = __shfl(corr, g * 4 + 2);
                float c3 = __shfl(corr, g * 4 + 3);
#pragma unroll
                for (int fn = 0; fn < 4; ++fn) {
                    o[fn][0] *= c0; o[fn][1] *= c1; o[fn][2] *= c2; o[fn][3] *= c3;
                }
            }

            float psum = 0.0f;
            unsigned pku[4][2];
#pragma unroll
            for (int f = 0; f < 4; ++f)
#pragma unroll
                for (int rp = 0; rp < 2; ++rp) {
                    float p0 = exp2f(st[f][2 * rp]     - m_i);
                    float p1 = exp2f(st[f][2 * rp + 1] - m_i);
                    psum += p0 + p1;
                    auto pk = __builtin_amdgcn_cvt_pkrtz(p0, p1);   // __fp16x2
                    union { decltype(pk) h; unsigned u; } cv;
                    cv.h = pk;
                    pku[f][rp] = cv.u;
                }
            psum += __shfl_xor(psum, 16);
            psum += __shfl_xor(psum, 32);
            l_i += psum;

            __builtin_amdgcn_s_setprio(1);
#pragma unroll
            for (int kk = 0; kk < 2; ++kk) {
                unsigned paw[4];
#pragma unroll
                for (int jp = 0; jp < 4; ++jp) {
                    int srcl = (((2 * g + (jp >> 1)) & 3) << 4) + li;
                    unsigned v0 = (unsigned)__shfl((int)pku[2 * kk][jp & 1], srcl);
                    unsigned v1 = (unsigned)__shfl((int)pku[2 * kk + 1][jp & 1], srcl);
                    paw[jp] = (g & 2) ? v1 : v0;
                }
                union { unsigned u[4]; f16x8 v; } pa_;
                pa_.u[0] = paw[0]; pa_.u[1] = paw[1]; pa_.u[2] = paw[2]; pa_.u[3] = paw[3];
                f16x8 pa = pa_.v;
#pragma unroll
                for (int fn = 0; fn < 4; ++fn) {
                    int drow = fn * 16 + li;
                    int vp = (kk * 4 + g) ^ (li & 7);
                    f16x8 vf = *(const f16x8*)(Vb + drow * 64 + vp * 8);
                    o[fn] = __builtin_amdgcn_mfma_f32_16x16x32_f16(pa, vf, o[fn], 0, 0, 0);
                }
            }
            __builtin_amdgcn_s_setprio(0);
        }
        __builtin_amdgcn_sched_barrier(0);
        __builtin_amdgcn_s_barrier();   // protects slot nb from next iter's STAGE
    }

#pragma unroll
    for (int reg = 0; reg < 4; ++reg) {
        float linv = 1.0f / __shfl(l_i, g * 4 + reg);
        int row = Q0 + w * 16 + g * 4 + reg;
#pragma unroll
        for (int fn = 0; fn < 4; ++fn)
            Ob[(size_t)row * HIDD + h * 64 + fn * 16 + li] = (_Float16)(o[fn][reg] * linv);
    }
}

// ---------------------------------------------------------------- launch
extern "C" void kernel_launch(void* const* d_in, const int* in_sizes, int n_in,
                              void* d_out, int out_size, void* d_ws, size_t ws_size,
                              hipStream_t stream) {
    const float* hs   = (const float*)d_in[0];
    const float* Wq   = (const float*)d_in[2];
    const float* Wk   = (const float*)d_in[3];
    const float* Wv   = (const float*)d_in[4];
    const float* Wo   = (const float*)d_in[5];
    const float* qlnw = (const float*)d_in[6];
    const float* klnw = (const float*)d_in[7];
    const float* qa   = (const float*)d_in[8];
    const float* ka   = (const float*)d_in[9];
    const float* va   = (const float*)d_in[10];
    const float* oa   = (const float*)d_in[11];

    char* ws = (char*)d_ws;
    _Float16* hsb   = (_Float16*)ws;                 ws += (size_t)SS * HIDD * 2;
    _Float16* wqkvb = (_Float16*)ws;                 ws += (size_t)NQKV * HIDD * 2;
    _Float16* wob   = (_Float16*)ws;                 ws += (size_t)HIDD * HIDD * 2;
    float2*   rtab  = (float2*)ws;                   ws += (size_t)SS * 32 * 8;          // 512 KB
    _Float16* Qhd   = (_Float16*)ws;                 ws += (size_t)HH * SS * DD * 2;
    _Float16* Khd   = (_Float16*)ws;                 ws += (size_t)KVHH * SS * DD * 2;
    _Float16* Vhd   = (_Float16*)ws;                 ws += (size_t)KVHH * SS * DD * 2;
    _Float16* Vtd   = (_Float16*)ws;                 ws += (size_t)KVHH * SS * DD * 2;
    _Float16* attnb = (_Float16*)ws;                 ws += (size_t)SS * HIDD * 2;

    rope_tab_init<<<256, 256, 0, stream>>>(rtab);

    cvt_all<<<12480, 256, 0, stream>>>(hs, Wq, Wk, Wv, Wo, hsb, wqkvb, wob, qa, ka, va, oa);

    // fused QKV projection + LN + RoPE (64-row M-tiles: 672 blocks)
    gemm_qkv<<<dim3(NQKV / 128, SS / 64), 512, 0, stream>>>(hsb, wqkvb, qlnw, klnw, rtab,
                                                            Qhd, Khd, Vhd, SS, NQKV, HIDD);

    transpose_v<<<dim3(SS / 64, KVHH), 256, 0, stream>>>(Vhd, Vtd);

    // grid (h, qb): stride-256 CU siblings get spread qb -> balanced chunk work
    attn_mfma<<<dim3(HH, SS / 64), 256, 0, stream>>>(Qhd, Khd, Vtd, attnb);

    gemm_bt_f16<<<dim3(HIDD / 128, SS / 64), 512, 0, stream>>>(attnb, wob, (float*)d_out, SS, HIDD, HIDD);
}

// Round 20
// 118.241 us; speedup vs baseline: 1.0310x; 1.0310x over previous
//
#include <hip/hip_runtime.h>
#include <hip/hip_fp16.h>

#define SS 2048
#define HH 30
#define KVHH 6
#define DD 64
#define HIDD 1920
#define NQKV 2688   // 1920 (q) + 384 (k) + 384 (v)

typedef __attribute__((ext_vector_type(4))) float  f32x4;
typedef __attribute__((ext_vector_type(4))) float  float4v;
typedef __attribute__((ext_vector_type(8))) _Float16 f16x8;
typedef __attribute__((ext_vector_type(4))) _Float16 f16x4;

// ---------------------------------------------------------------- RoPE cos/sin table: tab[s*32+j] = {cos(s*f_j), sin(s*f_j)}
__global__ __launch_bounds__(256) void rope_tab_init(float2* __restrict__ tab) {
    int idx = blockIdx.x * 256 + threadIdx.x;          // 0..65535 = s*32+j
    int s = idx >> 5, j = idx & 31;
    float f = exp2f(-13.287712379549449f * (float)j * (1.0f / 32.0f));
    float ang = (float)s * f;
    float sn, cs;
    sincosf(ang, &sn, &cs);
    tab[idx] = make_float2(cs, sn);
}

// ---------------------------------------------------------------- fused f32->f16 cvt (*alpha), 5 regions, 1024 elems/block
__global__ __launch_bounds__(256) void cvt_all(const float* __restrict__ hs,
                                               const float* __restrict__ Wq,
                                               const float* __restrict__ Wk,
                                               const float* __restrict__ Wv,
                                               const float* __restrict__ Wo,
                                               _Float16* __restrict__ hsb,
                                               _Float16* __restrict__ wqkvb,
                                               _Float16* __restrict__ wob,
                                               const float* __restrict__ qa,
                                               const float* __restrict__ ka,
                                               const float* __restrict__ va,
                                               const float* __restrict__ oa) {
    int b = blockIdx.x;
    const float* in; _Float16* out; float a; int base;
    if (b < 3840)      { in = hs; out = hsb;              a = 1.0f;  base = b; }
    else if (b < 7440) { in = Wq; out = wqkvb;            a = qa[0]; base = b - 3840; }
    else if (b < 8160) { in = Wk; out = wqkvb + 3686400;  a = ka[0]; base = b - 7440; }
    else if (b < 8880) { in = Wv; out = wqkvb + 4423680;  a = va[0]; base = b - 8160; }
    else               { in = Wo; out = wob;              a = oa[0]; base = b - 8880; }
    int i = base * 1024 + threadIdx.x * 4;
    float4v v = *(const float4v*)(in + i);
    f16x4 o;
    o[0] = (_Float16)(v[0] * a);
    o[1] = (_Float16)(v[1] * a);
    o[2] = (_Float16)(v[2] * a);
    o[3] = (_Float16)(v[3] * a);
    *(f16x4*)(out + i) = o;
}

// ---------------------------------------------------------------- shared GEMM pieces
// 64x128 tile, BK=64, 8 waves as 4M x 2N, wave sub-tile 16x64.
// 2-slot double buffer (48 KB), counted vmcnt(3) + raw barriers.
#define GEMM_STAGE(buf, ktv)                                                                           \
    do {                                                                                               \
        {                                                                                              \
            int row = tid >> 3;                                                                        \
            int sl  = (tid & 7) ^ (row & 7);                                                           \
            const _Float16* gA = A + (size_t)(m0 + row) * K + (ktv) + sl * 8;                          \
            _Float16* lA = As[buf] + (size_t)(w * 64) * 8;                                             \
            __builtin_amdgcn_global_load_lds((const __attribute__((address_space(1))) unsigned int*)gA,\
                                             (__attribute__((address_space(3))) unsigned int*)lA, 16, 0, 0); \
        }                                                                                              \
        _Pragma("unroll")                                                                              \
        for (int it = 0; it < 2; ++it) {                                                               \
            int gg  = it * 512 + tid;                                                                  \
            int row = gg >> 3;                                                                         \
            int sl  = (gg & 7) ^ (row & 7);                                                            \
            const _Float16* gB = B + (size_t)(n0 + row) * K + (ktv) + sl * 8;                          \
            _Float16* lB = Bs[buf] + (size_t)(it * 512 + w * 64) * 8;                                  \
            __builtin_amdgcn_global_load_lds((const __attribute__((address_space(1))) unsigned int*)gB,\
                                             (__attribute__((address_space(3))) unsigned int*)lB, 16, 0, 0); \
        }                                                                                              \
    } while (0)

#define GEMM_BODY()                                                                                    \
    f32x4 acc[4];                                                                                      \
    _Pragma("unroll")                                                                                  \
    for (int b = 0; b < 4; ++b) acc[b] = (f32x4)0.0f;                                                  \
    GEMM_STAGE(0, 0);                                                                                  \
    const int nk = K >> 6;                                                                             \
    for (int t = 0; t < nk; ++t) {                                                                     \
        const int cur = t & 1;                                                                         \
        if (t + 1 < nk) {                                                                              \
            GEMM_STAGE(cur ^ 1, (t + 1) * 64);                                                         \
            asm volatile("s_waitcnt vmcnt(3)" ::: "memory");                                           \
        } else {                                                                                       \
            asm volatile("s_waitcnt vmcnt(0)" ::: "memory");                                           \
        }                                                                                              \
        __builtin_amdgcn_s_barrier();                                                                  \
        __builtin_amdgcn_sched_barrier(0);                                                             \
        _Pragma("unroll")                                                                              \
        for (int kk = 0; kk < 2; ++kk) {                                                               \
            f16x8 af, bf[4];                                                                           \
            {                                                                                          \
                int row = wm + (l & 15);                                                               \
                int s   = (kk * 4 + (l >> 4)) ^ (row & 7);                                             \
                af = *(const f16x8*)(As[cur] + row * 64 + s * 8);                                      \
            }                                                                                          \
            _Pragma("unroll")                                                                          \
            for (int fn = 0; fn < 4; ++fn) {                                                           \
                int row = wn + fn * 16 + (l & 15);                                                     \
                int s   = (kk * 4 + (l >> 4)) ^ (row & 7);                                             \
                bf[fn] = *(const f16x8*)(Bs[cur] + row * 64 + s * 8);                                  \
            }                                                                                          \
            _Pragma("unroll")                                                                          \
            for (int fn = 0; fn < 4; ++fn)                                                             \
                acc[fn] = __builtin_amdgcn_mfma_f32_16x16x32_f16(af, bf[fn], acc[fn], 0, 0, 0);        \
        }                                                                                              \
        __builtin_amdgcn_sched_barrier(0);                                                             \
        __builtin_amdgcn_s_barrier();                                                                  \
    }

// ---------------------------------------------------------------- QKV GEMM with fused LN+RoPE epilogue
__global__ __launch_bounds__(512) void gemm_qkv(const _Float16* __restrict__ A,
                                                const _Float16* __restrict__ B,
                                                const float* __restrict__ qlnw,
                                                const float* __restrict__ klnw,
                                                const float2* __restrict__ tab,
                                                _Float16* __restrict__ Qh,
                                                _Float16* __restrict__ Kh,
                                                _Float16* __restrict__ Vh,
                                                int M, int N, int K) {
    __shared__ __align__(16) _Float16 As[2][64 * 64];
    __shared__ __align__(16) _Float16 Bs[2][128 * 64];
    const int tid = threadIdx.x;
    const int l   = tid & 63;
    const int w   = tid >> 6;                 // 0..7
    const int wm  = (w >> 1) * 16;            // 4 waves in M (16 rows each)
    const int wn  = (w & 1) * 64;             // 2 waves in N
    const int g = l >> 4, li = l & 15;

    const int gx  = gridDim.x;
    const int nwg = gx * gridDim.y;
    int bid = blockIdx.y * gx + blockIdx.x;
    int lid = (bid & 7) * (nwg >> 3) + (bid >> 3);
    int gsz = gx * 8;
    int grp = lid / gsz;
    int r   = lid - grp * gsz;
    int bx  = r >> 3;
    int by  = grp * 8 + (r & 7);

    const int m0 = by * 64;
    const int n0 = bx * 128;

    GEMM_BODY();

    // ---- fused epilogue ----------------------------------------------------
    const int unit = (n0 >> 6) + (w & 1);
    if (unit < 36) {          // Q or K head: LayerNorm + RoPE
        const float* lwp = (unit < 30) ? (qlnw + unit * 64) : (klnw + (unit - 30) * 64);
        float lw[4];
#pragma unroll
        for (int fn = 0; fn < 4; ++fn) lw[fn] = lwp[fn * 16 + li];
        _Float16* outp = (unit < 30) ? (Qh + (size_t)unit * SS * 64)
                                     : (Kh + (size_t)(unit - 30) * SS * 64);
        const float qs = (unit < 30) ? 0.18033688011112042f : 1.0f;
#pragma unroll
        for (int j = 0; j < 4; ++j) {
            float x0 = acc[0][j], x1 = acc[1][j], x2 = acc[2][j], x3 = acc[3][j];
            float s1 = x0 + x1 + x2 + x3;
            float s2 = x0 * x0 + x1 * x1 + x2 * x2 + x3 * x3;
#pragma unroll
            for (int off = 1; off < 16; off <<= 1) {
                s1 += __shfl_xor(s1, off);
                s2 += __shfl_xor(s2, off);
            }
            float mu  = s1 * (1.0f / 64.0f);
            float var = s2 * (1.0f / 64.0f) - mu * mu;   // biased var
            float rst = rsqrtf(var + 1e-5f);
            float n0_ = (x0 - mu) * rst * lw[0];
            float n1_ = (x1 - mu) * rst * lw[1];
            float n2_ = (x2 - mu) * rst * lw[2];
            float n3_ = (x3 - mu) * rst * lw[3];
            int srow = m0 + wm + g * 4 + j;
            float2 cs0 = tab[srow * 32 + li];
            float2 cs1 = tab[srow * 32 + 16 + li];
            float o0 = (n0_ * cs0.x - n2_ * cs0.y) * qs;
            float o1 = (n1_ * cs1.x - n3_ * cs1.y) * qs;
            float o2 = (n2_ * cs0.x + n0_ * cs0.y) * qs;
            float o3 = (n3_ * cs1.x + n1_ * cs1.y) * qs;
            _Float16* rp = outp + (size_t)srow * 64 + li;
            rp[0]  = (_Float16)o0;
            rp[16] = (_Float16)o1;
            rp[32] = (_Float16)o2;
            rp[48] = (_Float16)o3;
        }
    } else {                  // V head: passthrough f16 store (head-major)
        _Float16* outp = Vh + (size_t)(unit - 36) * SS * 64;
#pragma unroll
        for (int j = 0; j < 4; ++j) {
            int srow = m0 + wm + g * 4 + j;
            _Float16* rp = outp + (size_t)srow * 64 + li;
            rp[0]  = (_Float16)acc[0][j];
            rp[16] = (_Float16)acc[1][j];
            rp[32] = (_Float16)acc[2][j];
            rp[48] = (_Float16)acc[3][j];
        }
    }
}

// ---------------------------------------------------------------- O-projection GEMM (f32 out)
__global__ __launch_bounds__(512) void gemm_bt_f16(const _Float16* __restrict__ A,
                                                   const _Float16* __restrict__ B,
                                                   float* __restrict__ C,
                                                   int M, int N, int K) {
    __shared__ __align__(16) _Float16 As[2][64 * 64];
    __shared__ __align__(16) _Float16 Bs[2][128 * 64];
    const int tid = threadIdx.x;
    const int l   = tid & 63;
    const int w   = tid >> 6;
    const int wm  = (w >> 1) * 16;
    const int wn  = (w & 1) * 64;

    const int gx  = gridDim.x;
    const int nwg = gx * gridDim.y;
    int bid = blockIdx.y * gx + blockIdx.x;
    int lid = (bid & 7) * (nwg >> 3) + (bid >> 3);
    int gsz = gx * 8;
    int grp = lid / gsz;
    int r   = lid - grp * gsz;
    int bx  = r >> 3;
    int by  = grp * 8 + (r & 7);

    const int m0 = by * 64;
    const int n0 = bx * 128;

    GEMM_BODY();

#pragma unroll
    for (int fn = 0; fn < 4; ++fn)
#pragma unroll
        for (int j = 0; j < 4; ++j) {
            int rr = m0 + wm + (l >> 4) * 4 + j;
            int cc = n0 + wn + fn * 16 + (l & 15);
            C[(size_t)rr * N + cc] = acc[fn][j];
        }
}

// ---------------------------------------------------------------- V transpose: Vh[h][s][d] -> Vt[h][d][s]
__global__ __launch_bounds__(256) void transpose_v(const _Float16* __restrict__ Vh,
                                                   _Float16* __restrict__ Vt) {
    __shared__ _Float16 T[64][68];
    const int s0 = blockIdx.x * 64;
    const int h  = blockIdx.y;
    const int tid = threadIdx.x;
#pragma unroll
    for (int pass = 0; pass < 2; ++pass) {
        int idx = pass * 256 + tid;
        int r = idx >> 3, d0 = (idx & 7) * 8;
        f16x8 v = *(const f16x8*)(Vh + ((size_t)(h * SS + s0 + r)) * 64 + d0);
#pragma unroll
        for (int j = 0; j < 8; ++j) T[r][d0 + j] = v[j];
    }
    __syncthreads();
#pragma unroll
    for (int pass = 0; pass < 2; ++pass) {
        int idx = pass * 256 + tid;
        int d = idx >> 3, c0 = (idx & 7) * 8;
        f16x8 o;
#pragma unroll
        for (int j = 0; j < 8; ++j) o[j] = T[c0 + j][d];
        *(f16x8*)(Vt + ((size_t)(h * 64 + d)) * SS + s0 + c0) = o;
    }
}

// ---------------------------------------------------------------- MFMA sliding-window attention
// Empirical-best structure (R18): 4 waves x 16 q-rows, swapped QK^T, 2-slot
// double-buffered K/V staging, counted vmcnt + raw barriers, LDS P-bounce
// (R19 shuffle variant regressed: ds_bpermute doubled LDS-pipe conflicts),
// exp2-domain softmax with defer-max THR 8, cvt_pkrtz P-pack, (h,qb) grid.
#define ATTN_STAGE(buf, c)                                                                             \
    do {                                                                                               \
        _Pragma("unroll")                                                                              \
        for (int t = 0; t < 2; ++t) {                                                                  \
            int rloc = w * 16 + t * 8 + (l >> 3);                                                      \
            int ss = (l & 7) ^ (l >> 3);                                                               \
            const _Float16* gK = Kh + ((size_t)kvh * SS + (c) * 64 + rloc) * 64 + ss * 8;              \
            const _Float16* gV = Vt + ((size_t)kvh * 64 + rloc) * SS + (c) * 64 + ss * 8;              \
            _Float16* lK = Ks[buf] + (w * 16 + t * 8) * 64;                                            \
            _Float16* lV = Vs[buf] + (w * 16 + t * 8) * 64;                                            \
            __builtin_amdgcn_global_load_lds((const __attribute__((address_space(1))) unsigned int*)gK,\
                                             (__attribute__((address_space(3))) unsigned int*)lK, 16, 0, 0); \
            __builtin_amdgcn_global_load_lds((const __attribute__((address_space(1))) unsigned int*)gV,\
                                             (__attribute__((address_space(3))) unsigned int*)lV, 16, 0, 0); \
        }                                                                                              \
    } while (0)

__global__ __launch_bounds__(256) void attn_mfma(const _Float16* __restrict__ Qh,
                                                 const _Float16* __restrict__ Kh,
                                                 const _Float16* __restrict__ Vt,
                                                 _Float16* __restrict__ Ob) {
    __shared__ __align__(16) _Float16 Ks[2][64 * 64];
    __shared__ __align__(16) _Float16 Vs[2][64 * 64];
    __shared__ __align__(16) _Float16 Ps[4][16 * 64];

    const int qb = 31 - blockIdx.y;          // long blocks dispatch first
    const int h = blockIdx.x;                // x = head: balances qb across CUs
    const int Q0 = qb * 64;
    const int kvh = h / 5;
    const int tid = threadIdx.x, l = tid & 63, w = tid >> 6;
    const int g = l >> 4, li = l & 15;
    const int qabs = Q0 + w * 16 + li;
    const int qw = Q0 + w * 16;

    f16x8 qf[2];
#pragma unroll
    for (int dk = 0; dk < 2; ++dk)
        qf[dk] = *(const f16x8*)(Qh + ((size_t)h * SS + qabs) * 64 + dk * 32 + g * 8);
    asm volatile("s_waitcnt vmcnt(0)" ::: "memory");   // qf resolved before counting starts

    float m_i = -1e20f, l_i = 0.0f;          // floor -1e20: masked rows stay p=0
    f32x4 o[4];
#pragma unroll
    for (int fn = 0; fn < 4; ++fn) o[fn] = (f32x4)0.0f;

    const int c_lo = (Q0 >= 1023) ? ((Q0 - 1023) >> 6) : 0;
    const int c_hi = qb;

    ATTN_STAGE(0, c_lo);

    for (int c = c_lo; c <= c_hi; ++c) {
        const int nb = (c - c_lo) & 1;
        if (c < c_hi) {
            ATTN_STAGE(nb ^ 1, c + 1);                       // flies across both barriers
            asm volatile("s_waitcnt vmcnt(4)" ::: "memory"); // stage(c) landed
        } else {
            asm volatile("s_waitcnt vmcnt(0)" ::: "memory"); // last chunk: drain
        }
        __builtin_amdgcn_s_barrier();
        __builtin_amdgcn_sched_barrier(0);

        if (c * 64 <= qw + 15 && c * 64 + 63 >= qw - 1023) {
            const _Float16* Kb = Ks[nb];
            const _Float16* Vb = Vs[nb];
            const bool full = (c * 64 + 63 <= qw) && (c * 64 >= qw + 15 - 1023);

            f32x4 st[4];
#pragma unroll
            for (int f = 0; f < 4; ++f) st[f] = (f32x4)0.0f;
            __builtin_amdgcn_s_setprio(1);
#pragma unroll
            for (int dk = 0; dk < 2; ++dk) {
#pragma unroll
                for (int f = 0; f < 4; ++f) {
                    int ps = (dk * 4 + g) ^ (li & 7);
                    f16x8 kf = *(const f16x8*)(Kb + (f * 16 + li) * 64 + ps * 8);
                    st[f] = __builtin_amdgcn_mfma_f32_16x16x32_f16(kf, qf[dk], st[f], 0, 0, 0);
                }
            }
            __builtin_amdgcn_s_setprio(0);

            if (!full) {
#pragma unroll
                for (int f = 0; f < 4; ++f)
#pragma unroll
                    for (int reg = 0; reg < 4; ++reg) {
                        int kab = c * 64 + f * 16 + g * 4 + reg;
                        bool valid = (kab <= qabs) && (qabs - kab < 1024);
                        st[f][reg] = valid ? st[f][reg] : -1e30f;
                    }
            }
            float mx = -1e30f;
#pragma unroll
            for (int f = 0; f < 4; ++f)
#pragma unroll
                for (int reg = 0; reg < 4; ++reg) mx = fmaxf(mx, st[f][reg]);
            mx = fmaxf(mx, __shfl_xor(mx, 16));
            mx = fmaxf(mx, __shfl_xor(mx, 32));

            if (__any(mx > m_i + 8.0f)) {        // defer-max: P bounded by 2^8
                float m_new = fmaxf(m_i, mx);
                float corr = exp2f(m_i - m_new);
                m_i = m_new;
                l_i *= corr;
                float c0 = __shfl(corr, g * 4 + 0);
                float c1 = __shfl(corr, g * 4 + 1);
                float c2 = __shfl(corr, g * 4 + 2);
                float c3 = __shfl(corr, g * 4 + 3);
#pragma unroll
                for (int fn = 0; fn < 4; ++fn) {
                    o[fn][0] *= c0; o[fn][1] *= c1; o[fn][2] *= c2; o[fn][3] *= c3;
                }
            }

            float psum = 0.0f;
            char* Pw = (char*)&Ps[w][0] + li * 128;
#pragma unroll
            for (int f = 0; f < 4; ++f)
#pragma unroll
                for (int rp = 0; rp < 2; ++rp) {
                    float p0 = exp2f(st[f][2 * rp]     - m_i);
                    float p1 = exp2f(st[f][2 * rp + 1] - m_i);
                    psum += p0 + p1;
                    auto pk = __builtin_amdgcn_cvt_pkrtz(p0, p1);   // __fp16x2, 1-op pack
                    int phys = (f * 2 + (g >> 1)) ^ (li & 7);
                    *(decltype(pk)*)(Pw + phys * 16 + (g & 1) * 8 + rp * 4) = pk;
                }
            psum += __shfl_xor(psum, 16);
            psum += __shfl_xor(psum, 32);
            l_i += psum;

            __builtin_amdgcn_s_setprio(1);
#pragma unroll
            for (int kk = 0; kk < 2; ++kk) {
                int pp = (kk * 4 + g) ^ (li & 7);
                f16x8 pa = *(const f16x8*)(Pw + pp * 16);
#pragma unroll
                for (int fn = 0; fn < 4; ++fn) {
                    int drow = fn * 16 + li;
                    int vp = (kk * 4 + g) ^ (li & 7);
                    f16x8 vf = *(const f16x8*)(Vb + drow * 64 + vp * 8);
                    o[fn] = __builtin_amdgcn_mfma_f32_16x16x32_f16(pa, vf, o[fn], 0, 0, 0);
                }
            }
            __builtin_amdgcn_s_setprio(0);
        }
        __builtin_amdgcn_sched_barrier(0);
        __builtin_amdgcn_s_barrier();   // protects slot nb from next iter's STAGE
    }

#pragma unroll
    for (int reg = 0; reg < 4; ++reg) {
        float linv = 1.0f / __shfl(l_i, g * 4 + reg);
        int row = Q0 + w * 16 + g * 4 + reg;
#pragma unroll
        for (int fn = 0; fn < 4; ++fn)
            Ob[(size_t)row * HIDD + h * 64 + fn * 16 + li] = (_Float16)(o[fn][reg] * linv);
    }
}

// ---------------------------------------------------------------- launch
extern "C" void kernel_launch(void* const* d_in, const int* in_sizes, int n_in,
                              void* d_out, int out_size, void* d_ws, size_t ws_size,
                              hipStream_t stream) {
    const float* hs   = (const float*)d_in[0];
    const float* Wq   = (const float*)d_in[2];
    const float* Wk   = (const float*)d_in[3];
    const float* Wv   = (const float*)d_in[4];
    const float* Wo   = (const float*)d_in[5];
    const float* qlnw = (const float*)d_in[6];
    const float* klnw = (const float*)d_in[7];
    const float* qa   = (const float*)d_in[8];
    const float* ka   = (const float*)d_in[9];
    const float* va   = (const float*)d_in[10];
    const float* oa   = (const float*)d_in[11];

    char* ws = (char*)d_ws;
    _Float16* hsb   = (_Float16*)ws;                 ws += (size_t)SS * HIDD * 2;
    _Float16* wqkvb = (_Float16*)ws;                 ws += (size_t)NQKV * HIDD * 2;
    _Float16* wob   = (_Float16*)ws;                 ws += (size_t)HIDD * HIDD * 2;
    float2*   rtab  = (float2*)ws;                   ws += (size_t)SS * 32 * 8;          // 512 KB
    _Float16* Qhd   = (_Float16*)ws;                 ws += (size_t)HH * SS * DD * 2;
    _Float16* Khd   = (_Float16*)ws;                 ws += (size_t)KVHH * SS * DD * 2;
    _Float16* Vhd   = (_Float16*)ws;                 ws += (size_t)KVHH * SS * DD * 2;
    _Float16* Vtd   = (_Float16*)ws;                 ws += (size_t)KVHH * SS * DD * 2;
    _Float16* attnb = (_Float16*)ws;                 ws += (size_t)SS * HIDD * 2;

    rope_tab_init<<<256, 256, 0, stream>>>(rtab);

    cvt_all<<<12480, 256, 0, stream>>>(hs, Wq, Wk, Wv, Wo, hsb, wqkvb, wob, qa, ka, va, oa);

    // fused QKV projection + LN + RoPE (64-row M-tiles: 672 blocks)
    gemm_qkv<<<dim3(NQKV / 128, SS / 64), 512, 0, stream>>>(hsb, wqkvb, qlnw, klnw, rtab,
                                                            Qhd, Khd, Vhd, SS, NQKV, HIDD);

    transpose_v<<<dim3(SS / 64, KVHH), 256, 0, stream>>>(Vhd, Vtd);

    // grid (h, qb): stride-256 CU siblings get spread qb -> balanced chunk work
    attn_mfma<<<dim3(HH, SS / 64), 256, 0, stream>>>(Qhd, Khd, Vtd, attnb);

    gemm_bt_f16<<<dim3(HIDD / 128, SS / 64), 512, 0, stream>>>(attnb, wob, (float*)d_out, SS, HIDD, HIDD);
}

// Round 21
// 117.627 us; speedup vs baseline: 1.0364x; 1.0052x over previous
//
#include <hip/hip_runtime.h>
#include <hip/hip_fp16.h>

#define SS 2048
#define HH 30
#define KVHH 6
#define DD 64
#define HIDD 1920
#define NQKV 2688   // 1920 (q) + 384 (k) + 384 (v)

typedef __attribute__((ext_vector_type(4))) float  f32x4;
typedef __attribute__((ext_vector_type(4))) float  float4v;
typedef __attribute__((ext_vector_type(8))) _Float16 f16x8;
typedef __attribute__((ext_vector_type(4))) _Float16 f16x4;

// ---------------------------------------------------------------- RoPE cos/sin table: tab[s*32+j] = {cos(s*f_j), sin(s*f_j)}
__global__ __launch_bounds__(256) void rope_tab_init(float2* __restrict__ tab) {
    int idx = blockIdx.x * 256 + threadIdx.x;          // 0..65535 = s*32+j
    int s = idx >> 5, j = idx & 31;
    float f = exp2f(-13.287712379549449f * (float)j * (1.0f / 32.0f));
    float ang = (float)s * f;
    float sn, cs;
    sincosf(ang, &sn, &cs);
    tab[idx] = make_float2(cs, sn);
}

// ---------------------------------------------------------------- fused f32->f16 cvt (*alpha), 5 regions, 1024 elems/block
__global__ __launch_bounds__(256) void cvt_all(const float* __restrict__ hs,
                                               const float* __restrict__ Wq,
                                               const float* __restrict__ Wk,
                                               const float* __restrict__ Wv,
                                               const float* __restrict__ Wo,
                                               _Float16* __restrict__ hsb,
                                               _Float16* __restrict__ wqkvb,
                                               _Float16* __restrict__ wob,
                                               const float* __restrict__ qa,
                                               const float* __restrict__ ka,
                                               const float* __restrict__ va,
                                               const float* __restrict__ oa) {
    int b = blockIdx.x;
    const float* in; _Float16* out; float a; int base;
    if (b < 3840)      { in = hs; out = hsb;              a = 1.0f;  base = b; }
    else if (b < 7440) { in = Wq; out = wqkvb;            a = qa[0]; base = b - 3840; }
    else if (b < 8160) { in = Wk; out = wqkvb + 3686400;  a = ka[0]; base = b - 7440; }
    else if (b < 8880) { in = Wv; out = wqkvb + 4423680;  a = va[0]; base = b - 8160; }
    else               { in = Wo; out = wob;              a = oa[0]; base = b - 8880; }
    int i = base * 1024 + threadIdx.x * 4;
    float4v v = *(const float4v*)(in + i);
    f16x4 o;
    o[0] = (_Float16)(v[0] * a);
    o[1] = (_Float16)(v[1] * a);
    o[2] = (_Float16)(v[2] * a);
    o[3] = (_Float16)(v[3] * a);
    *(f16x4*)(out + i) = o;
}

// ---------------------------------------------------------------- shared GEMM pieces
// 64x128 tile, BK=64, 8 waves as 4M x 2N, wave sub-tile 16x64.
// 2-slot double buffer (48 KB), counted vmcnt(3) + raw barriers.
#define GEMM_STAGE(buf, ktv)                                                                           \
    do {                                                                                               \
        {                                                                                              \
            int row = tid >> 3;                                                                        \
            int sl  = (tid & 7) ^ (row & 7);                                                           \
            const _Float16* gA = A + (size_t)(m0 + row) * K + (ktv) + sl * 8;                          \
            _Float16* lA = As[buf] + (size_t)(w * 64) * 8;                                             \
            __builtin_amdgcn_global_load_lds((const __attribute__((address_space(1))) unsigned int*)gA,\
                                             (__attribute__((address_space(3))) unsigned int*)lA, 16, 0, 0); \
        }                                                                                              \
        _Pragma("unroll")                                                                              \
        for (int it = 0; it < 2; ++it) {                                                               \
            int gg  = it * 512 + tid;                                                                  \
            int row = gg >> 3;                                                                         \
            int sl  = (gg & 7) ^ (row & 7);                                                            \
            const _Float16* gB = B + (size_t)(n0 + row) * K + (ktv) + sl * 8;                          \
            _Float16* lB = Bs[buf] + (size_t)(it * 512 + w * 64) * 8;                                  \
            __builtin_amdgcn_global_load_lds((const __attribute__((address_space(1))) unsigned int*)gB,\
                                             (__attribute__((address_space(3))) unsigned int*)lB, 16, 0, 0); \
        }                                                                                              \
    } while (0)

#define GEMM_BODY()                                                                                    \
    f32x4 acc[4];                                                                                      \
    _Pragma("unroll")                                                                                  \
    for (int b = 0; b < 4; ++b) acc[b] = (f32x4)0.0f;                                                  \
    GEMM_STAGE(0, 0);                                                                                  \
    const int nk = K >> 6;                                                                             \
    for (int t = 0; t < nk; ++t) {                                                                     \
        const int cur = t & 1;                                                                         \
        if (t + 1 < nk) {                                                                              \
            GEMM_STAGE(cur ^ 1, (t + 1) * 64);                                                         \
            asm volatile("s_waitcnt vmcnt(3)" ::: "memory");                                           \
        } else {                                                                                       \
            asm volatile("s_waitcnt vmcnt(0)" ::: "memory");                                           \
        }                                                                                              \
        __builtin_amdgcn_s_barrier();                                                                  \
        __builtin_amdgcn_sched_barrier(0);                                                             \
        _Pragma("unroll")                                                                              \
        for (int kk = 0; kk < 2; ++kk) {                                                               \
            f16x8 af, bf[4];                                                                           \
            {                                                                                          \
                int row = wm + (l & 15);                                                               \
                int s   = (kk * 4 + (l >> 4)) ^ (row & 7);                                             \
                af = *(const f16x8*)(As[cur] + row * 64 + s * 8);                                      \
            }                                                                                          \
            _Pragma("unroll")                                                                          \
            for (int fn = 0; fn < 4; ++fn) {                                                           \
                int row = wn + fn * 16 + (l & 15);                                                     \
                int s   = (kk * 4 + (l >> 4)) ^ (row & 7);                                             \
                bf[fn] = *(const f16x8*)(Bs[cur] + row * 64 + s * 8);                                  \
            }                                                                                          \
            _Pragma("unroll")                                                                          \
            for (int fn = 0; fn < 4; ++fn)                                                             \
                acc[fn] = __builtin_amdgcn_mfma_f32_16x16x32_f16(af, bf[fn], acc[fn], 0, 0, 0);        \
        }                                                                                              \
        __builtin_amdgcn_sched_barrier(0);                                                             \
        __builtin_amdgcn_s_barrier();                                                                  \
    }

// ---------------------------------------------------------------- QKV GEMM with fused LN+RoPE epilogue
// V heads write V^T DIRECTLY (Vt[head][d][s]): thread's acc[fn][0..3] are 4
// consecutive s at fixed d -> one aligned 8 B f16x4 store per fn. Removes the
// transpose_v dispatch + the Vh round-trip.
__global__ __launch_bounds__(512) void gemm_qkv(const _Float16* __restrict__ A,
                                                const _Float16* __restrict__ B,
                                                const float* __restrict__ qlnw,
                                                const float* __restrict__ klnw,
                                                const float2* __restrict__ tab,
                                                _Float16* __restrict__ Qh,
                                                _Float16* __restrict__ Kh,
                                                _Float16* __restrict__ Vt,
                                                int M, int N, int K) {
    __shared__ __align__(16) _Float16 As[2][64 * 64];
    __shared__ __align__(16) _Float16 Bs[2][128 * 64];
    const int tid = threadIdx.x;
    const int l   = tid & 63;
    const int w   = tid >> 6;                 // 0..7
    const int wm  = (w >> 1) * 16;            // 4 waves in M (16 rows each)
    const int wn  = (w & 1) * 64;             // 2 waves in N
    const int g = l >> 4, li = l & 15;

    const int gx  = gridDim.x;
    const int nwg = gx * gridDim.y;
    int bid = blockIdx.y * gx + blockIdx.x;
    int lid = (bid & 7) * (nwg >> 3) + (bid >> 3);
    int gsz = gx * 8;
    int grp = lid / gsz;
    int r   = lid - grp * gsz;
    int bx  = r >> 3;
    int by  = grp * 8 + (r & 7);

    const int m0 = by * 64;
    const int n0 = bx * 128;

    GEMM_BODY();

    // ---- fused epilogue ----------------------------------------------------
    const int unit = (n0 >> 6) + (w & 1);
    if (unit < 36) {          // Q or K head: LayerNorm + RoPE
        const float* lwp = (unit < 30) ? (qlnw + unit * 64) : (klnw + (unit - 30) * 64);
        float lw[4];
#pragma unroll
        for (int fn = 0; fn < 4; ++fn) lw[fn] = lwp[fn * 16 + li];
        _Float16* outp = (unit < 30) ? (Qh + (size_t)unit * SS * 64)
                                     : (Kh + (size_t)(unit - 30) * SS * 64);
        const float qs = (unit < 30) ? 0.18033688011112042f : 1.0f;
#pragma unroll
        for (int j = 0; j < 4; ++j) {
            float x0 = acc[0][j], x1 = acc[1][j], x2 = acc[2][j], x3 = acc[3][j];
            float s1 = x0 + x1 + x2 + x3;
            float s2 = x0 * x0 + x1 * x1 + x2 * x2 + x3 * x3;
#pragma unroll
            for (int off = 1; off < 16; off <<= 1) {
                s1 += __shfl_xor(s1, off);
                s2 += __shfl_xor(s2, off);
            }
            float mu  = s1 * (1.0f / 64.0f);
            float var = s2 * (1.0f / 64.0f) - mu * mu;   // biased var
            float rst = rsqrtf(var + 1e-5f);
            float n0_ = (x0 - mu) * rst * lw[0];
            float n1_ = (x1 - mu) * rst * lw[1];
            float n2_ = (x2 - mu) * rst * lw[2];
            float n3_ = (x3 - mu) * rst * lw[3];
            int srow = m0 + wm + g * 4 + j;
            float2 cs0 = tab[srow * 32 + li];
            float2 cs1 = tab[srow * 32 + 16 + li];
            float o0 = (n0_ * cs0.x - n2_ * cs0.y) * qs;
            float o1 = (n1_ * cs1.x - n3_ * cs1.y) * qs;
            float o2 = (n2_ * cs0.x + n0_ * cs0.y) * qs;
            float o3 = (n3_ * cs1.x + n1_ * cs1.y) * qs;
            _Float16* rp = outp + (size_t)srow * 64 + li;
            rp[0]  = (_Float16)o0;
            rp[16] = (_Float16)o1;
            rp[32] = (_Float16)o2;
            rp[48] = (_Float16)o3;
        }
    } else {                  // V head: direct V^T store (Vt[head][d][s])
        _Float16* outp = Vt + (size_t)(unit - 36) * 64 * SS;
        const int srow0 = m0 + wm + g * 4;   // multiple of 4 -> 8 B aligned
#pragma unroll
        for (int fn = 0; fn < 4; ++fn) {
            f16x4 v4;
            v4[0] = (_Float16)acc[fn][0];
            v4[1] = (_Float16)acc[fn][1];
            v4[2] = (_Float16)acc[fn][2];
            v4[3] = (_Float16)acc[fn][3];
            *(f16x4*)(outp + (size_t)(fn * 16 + li) * SS + srow0) = v4;
        }
    }
}

// ---------------------------------------------------------------- O-projection GEMM (f32 out)
__global__ __launch_bounds__(512) void gemm_bt_f16(const _Float16* __restrict__ A,
                                                   const _Float16* __restrict__ B,
                                                   float* __restrict__ C,
                                                   int M, int N, int K) {
    __shared__ __align__(16) _Float16 As[2][64 * 64];
    __shared__ __align__(16) _Float16 Bs[2][128 * 64];
    const int tid = threadIdx.x;
    const int l   = tid & 63;
    const int w   = tid >> 6;
    const int wm  = (w >> 1) * 16;
    const int wn  = (w & 1) * 64;

    const int gx  = gridDim.x;
    const int nwg = gx * gridDim.y;
    int bid = blockIdx.y * gx + blockIdx.x;
    int lid = (bid & 7) * (nwg >> 3) + (bid >> 3);
    int gsz = gx * 8;
    int grp = lid / gsz;
    int r   = lid - grp * gsz;
    int bx  = r >> 3;
    int by  = grp * 8 + (r & 7);

    const int m0 = by * 64;
    const int n0 = bx * 128;

    GEMM_BODY();

#pragma unroll
    for (int fn = 0; fn < 4; ++fn)
#pragma unroll
        for (int j = 0; j < 4; ++j) {
            int rr = m0 + wm + (l >> 4) * 4 + j;
            int cc = n0 + wn + fn * 16 + (l & 15);
            C[(size_t)rr * N + cc] = acc[fn][j];
        }
}

// ---------------------------------------------------------------- MFMA sliding-window attention (R20 structure)
#define ATTN_STAGE(buf, c)                                                                             \
    do {                                                                                               \
        _Pragma("unroll")                                                                              \
        for (int t = 0; t < 2; ++t) {                                                                  \
            int rloc = w * 16 + t * 8 + (l >> 3);                                                      \
            int ss = (l & 7) ^ (l >> 3);                                                               \
            const _Float16* gK = Kh + ((size_t)kvh * SS + (c) * 64 + rloc) * 64 + ss * 8;              \
            const _Float16* gV = Vt + ((size_t)kvh * 64 + rloc) * SS + (c) * 64 + ss * 8;              \
            _Float16* lK = Ks[buf] + (w * 16 + t * 8) * 64;                                            \
            _Float16* lV = Vs[buf] + (w * 16 + t * 8) * 64;                                            \
            __builtin_amdgcn_global_load_lds((const __attribute__((address_space(1))) unsigned int*)gK,\
                                             (__attribute__((address_space(3))) unsigned int*)lK, 16, 0, 0); \
            __builtin_amdgcn_global_load_lds((const __attribute__((address_space(1))) unsigned int*)gV,\
                                             (__attribute__((address_space(3))) unsigned int*)lV, 16, 0, 0); \
        }                                                                                              \
    } while (0)

__global__ __launch_bounds__(256) void attn_mfma(const _Float16* __restrict__ Qh,
                                                 const _Float16* __restrict__ Kh,
                                                 const _Float16* __restrict__ Vt,
                                                 _Float16* __restrict__ Ob) {
    __shared__ __align__(16) _Float16 Ks[2][64 * 64];
    __shared__ __align__(16) _Float16 Vs[2][64 * 64];
    __shared__ __align__(16) _Float16 Ps[4][16 * 64];

    const int qb = 31 - blockIdx.y;          // long blocks dispatch first
    const int h = blockIdx.x;                // x = head: balances qb across CUs
    const int Q0 = qb * 64;
    const int kvh = h / 5;
    const int tid = threadIdx.x, l = tid & 63, w = tid >> 6;
    const int g = l >> 4, li = l & 15;
    const int qabs = Q0 + w * 16 + li;
    const int qw = Q0 + w * 16;

    f16x8 qf[2];
#pragma unroll
    for (int dk = 0; dk < 2; ++dk)
        qf[dk] = *(const f16x8*)(Qh + ((size_t)h * SS + qabs) * 64 + dk * 32 + g * 8);
    asm volatile("s_waitcnt vmcnt(0)" ::: "memory");   // qf resolved before counting starts

    float m_i = -1e20f, l_i = 0.0f;          // floor -1e20: masked rows stay p=0
    f32x4 o[4];
#pragma unroll
    for (int fn = 0; fn < 4; ++fn) o[fn] = (f32x4)0.0f;

    const int c_lo = (Q0 >= 1023) ? ((Q0 - 1023) >> 6) : 0;
    const int c_hi = qb;

    ATTN_STAGE(0, c_lo);

    for (int c = c_lo; c <= c_hi; ++c) {
        const int nb = (c - c_lo) & 1;
        if (c < c_hi) {
            ATTN_STAGE(nb ^ 1, c + 1);                       // flies across both barriers
            asm volatile("s_waitcnt vmcnt(4)" ::: "memory"); // stage(c) landed
        } else {
            asm volatile("s_waitcnt vmcnt(0)" ::: "memory"); // last chunk: drain
        }
        __builtin_amdgcn_s_barrier();
        __builtin_amdgcn_sched_barrier(0);

        if (c * 64 <= qw + 15 && c * 64 + 63 >= qw - 1023) {
            const _Float16* Kb = Ks[nb];
            const _Float16* Vb = Vs[nb];
            const bool full = (c * 64 + 63 <= qw) && (c * 64 >= qw + 15 - 1023);

            f32x4 st[4];
#pragma unroll
            for (int f = 0; f < 4; ++f) st[f] = (f32x4)0.0f;
            __builtin_amdgcn_s_setprio(1);
#pragma unroll
            for (int dk = 0; dk < 2; ++dk) {
#pragma unroll
                for (int f = 0; f < 4; ++f) {
                    int ps = (dk * 4 + g) ^ (li & 7);
                    f16x8 kf = *(const f16x8*)(Kb + (f * 16 + li) * 64 + ps * 8);
                    st[f] = __builtin_amdgcn_mfma_f32_16x16x32_f16(kf, qf[dk], st[f], 0, 0, 0);
                }
            }
            __builtin_amdgcn_s_setprio(0);

            if (!full) {
#pragma unroll
                for (int f = 0; f < 4; ++f)
#pragma unroll
                    for (int reg = 0; reg < 4; ++reg) {
                        int kab = c * 64 + f * 16 + g * 4 + reg;
                        bool valid = (kab <= qabs) && (qabs - kab < 1024);
                        st[f][reg] = valid ? st[f][reg] : -1e30f;
                    }
            }
            // log-depth max tree (max3-fusable)
            float mf0 = fmaxf(fmaxf(st[0][0], st[0][1]), fmaxf(st[0][2], st[0][3]));
            float mf1 = fmaxf(fmaxf(st[1][0], st[1][1]), fmaxf(st[1][2], st[1][3]));
            float mf2 = fmaxf(fmaxf(st[2][0], st[2][1]), fmaxf(st[2][2], st[2][3]));
            float mf3 = fmaxf(fmaxf(st[3][0], st[3][1]), fmaxf(st[3][2], st[3][3]));
            float mx = fmaxf(fmaxf(mf0, mf1), fmaxf(mf2, mf3));
            mx = fmaxf(mx, __shfl_xor(mx, 16));
            mx = fmaxf(mx, __shfl_xor(mx, 32));

            if (__any(mx > m_i + 8.0f)) {        // defer-max: P bounded by 2^8
                float m_new = fmaxf(m_i, mx);
                float corr = exp2f(m_i - m_new);
                m_i = m_new;
                l_i *= corr;
                float c0 = __shfl(corr, g * 4 + 0);
                float c1 = __shfl(corr, g * 4 + 1);
                float c2 = __shfl(corr, g * 4 + 2);
                float c3 = __shfl(corr, g * 4 + 3);
#pragma unroll
                for (int fn = 0; fn < 4; ++fn) {
                    o[fn][0] *= c0; o[fn][1] *= c1; o[fn][2] *= c2; o[fn][3] *= c3;
                }
            }

            float psum = 0.0f;
            char* Pw = (char*)&Ps[w][0] + li * 128;
#pragma unroll
            for (int f = 0; f < 4; ++f)
#pragma unroll
                for (int rp = 0; rp < 2; ++rp) {
                    float p0 = exp2f(st[f][2 * rp]     - m_i);
                    float p1 = exp2f(st[f][2 * rp + 1] - m_i);
                    psum += p0 + p1;
                    auto pk = __builtin_amdgcn_cvt_pkrtz(p0, p1);   // __fp16x2, 1-op pack
                    int phys = (f * 2 + (g >> 1)) ^ (li & 7);
                    *(decltype(pk)*)(Pw + phys * 16 + (g & 1) * 8 + rp * 4) = pk;
                }
            psum += __shfl_xor(psum, 16);
            psum += __shfl_xor(psum, 32);
            l_i += psum;

            __builtin_amdgcn_s_setprio(1);
#pragma unroll
            for (int kk = 0; kk < 2; ++kk) {
                int pp = (kk * 4 + g) ^ (li & 7);
                f16x8 pa = *(const f16x8*)(Pw + pp * 16);
#pragma unroll
                for (int fn = 0; fn < 4; ++fn) {
                    int drow = fn * 16 + li;
                    int vp = (kk * 4 + g) ^ (li & 7);
                    f16x8 vf = *(const f16x8*)(Vb + drow * 64 + vp * 8);
                    o[fn] = __builtin_amdgcn_mfma_f32_16x16x32_f16(pa, vf, o[fn], 0, 0, 0);
                }
            }
            __builtin_amdgcn_s_setprio(0);
        }
        __builtin_amdgcn_sched_barrier(0);
        __builtin_amdgcn_s_barrier();   // protects slot nb from next iter's STAGE
    }

#pragma unroll
    for (int reg = 0; reg < 4; ++reg) {
        float linv = 1.0f / __shfl(l_i, g * 4 + reg);
        int row = Q0 + w * 16 + g * 4 + reg;
#pragma unroll
        for (int fn = 0; fn < 4; ++fn)
            Ob[(size_t)row * HIDD + h * 64 + fn * 16 + li] = (_Float16)(o[fn][reg] * linv);
    }
}

// ---------------------------------------------------------------- launch
extern "C" void kernel_launch(void* const* d_in, const int* in_sizes, int n_in,
                              void* d_out, int out_size, void* d_ws, size_t ws_size,
                              hipStream_t stream) {
    const float* hs   = (const float*)d_in[0];
    const float* Wq   = (const float*)d_in[2];
    const float* Wk   = (const float*)d_in[3];
    const float* Wv   = (const float*)d_in[4];
    const float* Wo   = (const float*)d_in[5];
    const float* qlnw = (const float*)d_in[6];
    const float* klnw = (const float*)d_in[7];
    const float* qa   = (const float*)d_in[8];
    const float* ka   = (const float*)d_in[9];
    const float* va   = (const float*)d_in[10];
    const float* oa   = (const float*)d_in[11];

    char* ws = (char*)d_ws;
    _Float16* hsb   = (_Float16*)ws;                 ws += (size_t)SS * HIDD * 2;
    _Float16* wqkvb = (_Float16*)ws;                 ws += (size_t)NQKV * HIDD * 2;
    _Float16* wob   = (_Float16*)ws;                 ws += (size_t)HIDD * HIDD * 2;
    float2*   rtab  = (float2*)ws;                   ws += (size_t)SS * 32 * 8;          // 512 KB
    _Float16* Qhd   = (_Float16*)ws;                 ws += (size_t)HH * SS * DD * 2;
    _Float16* Khd   = (_Float16*)ws;                 ws += (size_t)KVHH * SS * DD * 2;
    _Float16* Vtd   = (_Float16*)ws;                 ws += (size_t)KVHH * SS * DD * 2;
    _Float16* attnb = (_Float16*)ws;                 ws += (size_t)SS * HIDD * 2;

    rope_tab_init<<<256, 256, 0, stream>>>(rtab);

    cvt_all<<<12480, 256, 0, stream>>>(hs, Wq, Wk, Wv, Wo, hsb, wqkvb, wob, qa, ka, va, oa);

    // fused QKV projection + LN + RoPE + direct V^T store (transpose fused away)
    gemm_qkv<<<dim3(NQKV / 128, SS / 64), 512, 0, stream>>>(hsb, wqkvb, qlnw, klnw, rtab,
                                                            Qhd, Khd, Vtd, SS, NQKV, HIDD);

    // grid (h, qb): stride-256 CU siblings get spread qb -> balanced chunk work
    attn_mfma<<<dim3(HH, SS / 64), 256, 0, stream>>>(Qhd, Khd, Vtd, attnb);

    gemm_bt_f16<<<dim3(HIDD / 128, SS / 64), 512, 0, stream>>>(attnb, wob, (float*)d_out, SS, HIDD, HIDD);
}